// Round 1
// baseline (432.254 us; speedup 1.0000x reference)
//
#include <hip/hip_runtime.h>
#include <math.h>

#define EPS 1e-6f

constexpr int B = 8, C = 3, H = 720, W = 1280;
constexpr int PAD = 20;           // absorbs left out-of-bounds targets (d in [0,20))
constexpr int SZ  = 1308;         // W + PAD + slack for x1==W zero-weight target; multiple of 4
constexpr int NT  = 320;          // 5 waves; W/2 == 2*NT (each thread owns 2 float2 columns)
// log2(1.414) in double precision
constexpr float K_LOG2 = 0.49978254377554356f;

// One block per (b, y) row. Forward SCATTER with native LDS f32 atomics:
// each source pixel contributes to exactly 2 outputs (1-D tent), so per row we
// do 2*W accumulator updates instead of the gather's 25*W tent evaluations.
// SoA accumulators; left pad of 20 absorbs OOB targets (never read back),
// matching the reference's valid-mask semantics. Reference's global
// 1.414^(-dmin) factor cancels in res/mask (same as previous kernel).
__global__ __launch_bounds__(NT) void splat_kernel(const float* __restrict__ im,
                                                   const float* __restrict__ disp,
                                                   float* __restrict__ out) {
    __shared__ __attribute__((aligned(16))) float s0[SZ];
    __shared__ __attribute__((aligned(16))) float s1[SZ];
    __shared__ __attribute__((aligned(16))) float s2[SZ];
    __shared__ __attribute__((aligned(16))) float sw[SZ];

    const int row = blockIdx.x;   // 0 .. B*H-1
    const int b = row / H;
    const int y = row - b * H;
    const int t = (int)threadIdx.x;

    const float* __restrict__ dr  = disp + (size_t)row * W;
    const float* __restrict__ im0 = im + ((size_t)(b * C + 0) * H + y) * W;
    const float* __restrict__ im1 = im + ((size_t)(b * C + 1) * H + y) * W;
    const float* __restrict__ im2 = im + ((size_t)(b * C + 2) * H + y) * W;

    // ---- issue global loads early (float2 = 8 B/lane, fully coalesced);
    //      their latency hides under the LDS zero-init below ----
    const float2 dA  = ((const float2*)dr )[t];
    const float2 dB  = ((const float2*)dr )[t + NT];
    const float2 c0A = ((const float2*)im0)[t];
    const float2 c0B = ((const float2*)im0)[t + NT];
    const float2 c1A = ((const float2*)im1)[t];
    const float2 c1B = ((const float2*)im1)[t + NT];
    const float2 c2A = ((const float2*)im2)[t];
    const float2 c2B = ((const float2*)im2)[t + NT];

    // ---- zero accumulators (vectorized b128 writes) ----
    {
        float4* z0 = (float4*)s0; float4* z1 = (float4*)s1;
        float4* z2 = (float4*)s2; float4* zw = (float4*)sw;
        const float4 zero4 = make_float4(0.f, 0.f, 0.f, 0.f);
        for (int i = t; i < SZ / 4; i += NT) {
            z0[i] = zero4; z1[i] = zero4; z2[i] = zero4; zw[i] = zero4;
        }
    }
    __syncthreads();

    // ---- scatter: each source pixel splats into 2 slots per array ----
    auto splat = [&](int x, float d, float v0, float v1, float v2) {
        const float w   = exp2f(K_LOG2 * d);   // 1.414^d
        const float tx  = (float)x - d;        // target x (flow is -d, y-flow = 0)
        const float x0f = floorf(tx);
        const float fc  = tx - x0f;            // in [0,1)
        const int   i   = (int)x0f + PAD;      // >= 0 since d < 20; <= W-1+PAD
        const float wb  = w * fc;              // weight at ceil  (ref's wc)
        const float wa  = w - wb;              // weight at floor (ref's wa)
        atomicAdd(&s0[i],     v0 * wa);
        atomicAdd(&s0[i + 1], v0 * wb);
        atomicAdd(&s1[i],     v1 * wa);
        atomicAdd(&s1[i + 1], v1 * wb);
        atomicAdd(&s2[i],     v2 * wa);
        atomicAdd(&s2[i + 1], v2 * wb);
        atomicAdd(&sw[i],     wa);
        atomicAdd(&sw[i + 1], wb);
    };
    splat(2 * t,              dA.x, c0A.x, c1A.x, c2A.x);
    splat(2 * t + 1,          dA.y, c0A.y, c1A.y, c2A.y);
    splat(2 * t + 2 * NT,     dB.x, c0B.x, c1B.x, c2B.x);
    splat(2 * t + 2 * NT + 1, dB.y, c0B.y, c1B.y, c2B.y);
    __syncthreads();

    // ---- normalize + store (float2, coalesced; v_rcp_f32 ~1 ulp) ----
    float* __restrict__ o0 = out + ((size_t)(b * C + 0) * H + y) * W;
    float* __restrict__ o1 = out + ((size_t)(b * C + 1) * H + y) * W;
    float* __restrict__ o2 = out + ((size_t)(b * C + 2) * H + y) * W;
    {
        const float2 q0 = *(const float2*)&s0[2 * t + PAD];
        const float2 q1 = *(const float2*)&s1[2 * t + PAD];
        const float2 q2 = *(const float2*)&s2[2 * t + PAD];
        const float2 qw = *(const float2*)&sw[2 * t + PAD];
        const float ix = __builtin_amdgcn_rcpf(fmaxf(qw.x, EPS));
        const float iy = __builtin_amdgcn_rcpf(fmaxf(qw.y, EPS));
        ((float2*)o0)[t] = make_float2(q0.x * ix, q0.y * iy);
        ((float2*)o1)[t] = make_float2(q1.x * ix, q1.y * iy);
        ((float2*)o2)[t] = make_float2(q2.x * ix, q2.y * iy);
    }
    {
        const float2 q0 = *(const float2*)&s0[2 * t + 2 * NT + PAD];
        const float2 q1 = *(const float2*)&s1[2 * t + 2 * NT + PAD];
        const float2 q2 = *(const float2*)&s2[2 * t + 2 * NT + PAD];
        const float2 qw = *(const float2*)&sw[2 * t + 2 * NT + PAD];
        const float ix = __builtin_amdgcn_rcpf(fmaxf(qw.x, EPS));
        const float iy = __builtin_amdgcn_rcpf(fmaxf(qw.y, EPS));
        ((float2*)o0)[t + NT] = make_float2(q0.x * ix, q0.y * iy);
        ((float2*)o1)[t + NT] = make_float2(q1.x * ix, q1.y * iy);
        ((float2*)o2)[t + NT] = make_float2(q2.x * ix, q2.y * iy);
    }
}

extern "C" void kernel_launch(void* const* d_in, const int* in_sizes, int n_in,
                              void* d_out, int out_size, void* d_ws, size_t ws_size,
                              hipStream_t stream) {
    const float* im   = (const float*)d_in[0];
    const float* disp = (const float*)d_in[1];
    float* out = (float*)d_out;
    (void)d_ws; (void)ws_size;

    splat_kernel<<<B * H, NT, 0, stream>>>(im, disp, out);
}